// Round 8
// baseline (199.868 us; speedup 1.0000x reference)
//
#include <hip/hip_runtime.h>

static constexpr int N = 50000;      // nodes
static constexpr int E = 1600000;    // edges
static constexpr int D = 128;        // feature dim (in == out)
static constexpr int NB = (N + 63) / 64;         // 782 buckets of 64 nodes
static constexpr int BINBLK = 512;               // bin blocks (E divides evenly)
static constexpr int CHUNK = E / BINBLK;         // 3125 edges per bin block
static constexpr int BKT_CAP = 3072;             // slab size; mean 2048, ~22 sigma

typedef __attribute__((ext_vector_type(8))) short short8;   // 8 bf16
typedef __attribute__((ext_vector_type(4))) float f32x4;    // 4 fp32
typedef __attribute__((ext_vector_type(2))) float f32x2;    // 2 fp32 (pk ops)

__device__ __forceinline__ uint bf16rne2(float a, float b) {
    uint ua = __float_as_uint(a), ub = __float_as_uint(b);
    ua += 0x7fffu + ((ua >> 16) & 1u);
    ub += 0x7fffu + ((ub >> 16) & 1u);
    return (ua >> 16) | (ub & 0xffff0000u);
}

// ------------------------------------------------------------ fused prep
// blocks [0,1563): x fp32->bf16 (N*D/4 = 1.6M uint2 items).
// [1563,1611): weight transpose+bf16.  block 1611: zero bucket cursors.
static constexpr int PREP_CVT_BLKS = (N * D / 4 + 1023) / 1024;  // 1563
static constexpr int PREP_W_BLKS   = 48;         // 128*384/1024
__global__ __launch_bounds__(1024) void prep_k(
        const float* __restrict__ x, const float* __restrict__ W,
        const float* __restrict__ Wr, ushort* __restrict__ xb,
        ushort* __restrict__ Wt, int* __restrict__ gcur) {
    int b = blockIdx.x, t = threadIdx.x;
    if (b < PREP_CVT_BLKS) {
        int i = b * 1024 + t;
        if (i < N * D / 4) {
            float4 v = ((const float4*)x)[i];
            uint2 o = { bf16rne2(v.x, v.y), bf16rne2(v.z, v.w) };
            ((uint2*)xb)[i] = o;
        }
    } else if (b < PREP_CVT_BLKS + PREP_W_BLKS) {
        int i = (b - PREP_CVT_BLKS) * 1024 + t;   // < 128*384
        int n = i / 384, r = i % 384;
        float v = (r < 256) ? W[(size_t)r * 128 + n]
                            : Wr[(size_t)(r - 256) * 128 + n];
        uint u = __float_as_uint(v);
        u += 0x7fffu + ((u >> 16) & 1u);
        Wt[(size_t)n * 384 + r] = (ushort)(u >> 16);
    } else {
        if (t < NB) gcur[t] = 0;
    }
}

// -------------------------------------------------- single-kernel binning
// Fixed slab per bucket: pay[bkt*BKT_CAP + ...]. A block reserves one run
// per touched bucket with a single global atomic (order within a bucket is
// non-deterministic -> only permutes fp-sum order, harmless).
// Payload: [15:0]=src, [21:16]=dst&63, [31:22]=u quantized /1023.
__device__ __forceinline__ int logical_blk() {
    // XCD swizzle: adjacent chunks -> same XCD so adjacent slab runs share L2.
    return (blockIdx.x & 7) * (BINBLK / 8) + (blockIdx.x >> 3);
}

__global__ __launch_bounds__(1024) void bin_k(const int* __restrict__ ei,
                                              const float* __restrict__ ea,
                                              int* __restrict__ gcur,
                                              uint* __restrict__ pay) {
    __shared__ int hist[NB];
    __shared__ int base[NB];
    int t = threadIdx.x;
    int b = logical_blk();
    for (int j = t; j < NB; j += 1024) hist[j] = 0;
    __syncthreads();
    int b0 = b * CHUNK;
    for (int i = b0 + t; i < b0 + CHUNK; i += 1024) {
        int dst = ei[E + i];
        if ((unsigned)dst < (unsigned)N) atomicAdd(&hist[dst >> 6], 1);
    }
    __syncthreads();
    for (int j = t; j < NB; j += 1024) {
        int c = hist[j];
        base[j] = c ? atomicAdd(&gcur[j], c) : 0;
        hist[j] = 0;
    }
    __syncthreads();
    for (int i = b0 + t; i < b0 + CHUNK; i += 1024) {
        int dst = ei[E + i];
        if ((unsigned)dst >= (unsigned)N) continue;
        int src = ei[i];
        float u = fminf(fmaxf(ea[i], 0.0f), 1.0f);
        uint u10 = (uint)(u * 1023.0f + 0.5f);
        int bkt = dst >> 6;
        int r = atomicAdd(&hist[bkt], 1);
        int pos = base[bkt] + r;
        if (pos < BKT_CAP)                       // slab overflow guard
            pay[(size_t)bkt * BKT_CAP + pos] =
                (u10 << 22) | ((uint)(dst & 63) << 16) | (uint)src;
    }
}

// --------------------------- fused per-bucket sort + per-node aggregation
// One 1024-thread WG per bucket (64 nodes). Phase 1: LDS-rank payload by
// dst_low6. Phase 2: 16 waves x 4 groups of 16 lanes; group = node; lane =
// 8 channels. 4-deep row-gather pipeline for L3-latency hiding.
__global__ __launch_bounds__(1024) void sortagg_k(
        const ushort* __restrict__ xb, const int* __restrict__ gcur,
        const uint* __restrict__ pay, ushort* __restrict__ a0b,
        ushort* __restrict__ a1b) {
    __shared__ uint srt[BKT_CAP];
    __shared__ int hist[64];
    __shared__ int off64[65];
    int b = blockIdx.x, t = threadIdx.x;
    int beg = b * BKT_CAP;
    int c = gcur[b];
    if (c > BKT_CAP) c = BKT_CAP;
    if (t < 64) hist[t] = 0;
    __syncthreads();
    uint mypay[3]; int myrank[3];
#pragma unroll
    for (int k = 0; k < 3; ++k) {
        int i = t + k * 1024;
        if (i < c) {
            uint p = pay[beg + i];
            mypay[k] = p;
            myrank[k] = atomicAdd(&hist[(p >> 16) & 63], 1);
        }
    }
    __syncthreads();
    if (t < 64) {
        int v = hist[t];
        int s = v;
        for (int d = 1; d < 64; d <<= 1) {
            int o = __shfl_up(s, d);
            if (t >= d) s += o;
        }
        off64[t] = s - v;             // exclusive
        if (t == 63) off64[64] = s;
    }
    __syncthreads();
#pragma unroll
    for (int k = 0; k < 3; ++k) {
        int i = t + k * 1024;
        if (i < c) {
            uint p = mypay[k];
            srt[off64[(p >> 16) & 63] + myrank[k]] = p;
        }
    }
    __syncthreads();

    // ---- aggregation: group (wave, grp) -> local node nloc
    int lane = t & 63;
    int wv   = t >> 6;            // 0..15
    int grp  = (lane >> 4);       // 0..3
    int cl   = lane & 15;         // channel block: chs [8*cl, 8*cl+8)
    int nloc = wv * 4 + grp;      // 0..63
    int s0 = off64[nloc], s1 = off64[nloc + 1];
    int deg = s1 - s0;

    f32x2 S[4], T[4];
#pragma unroll
    for (int q = 0; q < 4; ++q) { S[q] = 0.f; T[q] = 0.f; }

    int j = s0;
    for (; j + 3 < s1; j += 4) {           // 4-deep gather pipeline
        uint p[4];
        uint4 v[4];
#pragma unroll
        for (int d = 0; d < 4; ++d) p[d] = srt[j + d];
#pragma unroll
        for (int d = 0; d < 4; ++d)
            v[d] = *(const uint4*)(xb + (size_t)(p[d] & 0xffffu) * D + cl * 8);
#pragma unroll
        for (int d = 0; d < 4; ++d) {
            float u = (float)(p[d] >> 22) * (1.0f / 1023.0f);
            f32x2 u2 = {u, u};
            uint w[4] = {v[d].x, v[d].y, v[d].z, v[d].w};
#pragma unroll
            for (int q = 0; q < 4; ++q) {
                f32x2 xv = { __uint_as_float(w[q] << 16),
                             __uint_as_float(w[q] & 0xffff0000u) };
                S[q] += xv;
                T[q] = u2 * xv + T[q];
            }
        }
    }
    for (; j < s1; ++j) {
        uint p0 = srt[j];
        uint4 v0 = *(const uint4*)(xb + (size_t)(p0 & 0xffffu) * D + cl * 8);
        float u = (float)(p0 >> 22) * (1.0f / 1023.0f);
        f32x2 u2 = {u, u};
        uint w[4] = {v0.x, v0.y, v0.z, v0.w};
#pragma unroll
        for (int q = 0; q < 4; ++q) {
            f32x2 xv = { __uint_as_float(w[q] << 16),
                         __uint_as_float(w[q] & 0xffff0000u) };
            S[q] += xv;
            T[q] = u2 * xv + T[q];
        }
    }

    int node = b * 64 + nloc;
    if (node < N) {
        float inv = 1.0f / fmaxf((float)deg, 1.0f);
        uint4 oa = { bf16rne2((S[0].x - T[0].x) * inv, (S[0].y - T[0].y) * inv),
                     bf16rne2((S[1].x - T[1].x) * inv, (S[1].y - T[1].y) * inv),
                     bf16rne2((S[2].x - T[2].x) * inv, (S[2].y - T[2].y) * inv),
                     bf16rne2((S[3].x - T[3].x) * inv, (S[3].y - T[3].y) * inv) };
        uint4 ob = { bf16rne2(T[0].x * inv, T[0].y * inv),
                     bf16rne2(T[1].x * inv, T[1].y * inv),
                     bf16rne2(T[2].x * inv, T[2].y * inv),
                     bf16rne2(T[3].x * inv, T[3].y * inv) };
        *(uint4*)(a0b + (size_t)node * D + cl * 8) = oa;
        *(uint4*)(a1b + (size_t)node * D + cl * 8) = ob;
    }
}

// ------------------------------------------------------------- output GEMM
// out = [a0|a1|x] (M=50000, K=384, bf16) @ Wt^T + bias. 128x128 tile,
// 4 waves 2x2, 16x16x32 bf16 MFMA, BK=32.
__global__ __launch_bounds__(256) void gemm_k(
        const ushort* __restrict__ a0b, const ushort* __restrict__ a1b,
        const ushort* __restrict__ xb, const ushort* __restrict__ Wt,
        const float* __restrict__ bias, float* __restrict__ out) {
    constexpr int LST = 40;
    __shared__ ushort As[128 * LST];
    __shared__ ushort Bs[128 * LST];

    int t    = threadIdx.x;
    int lane = t & 63;
    int w    = t >> 6;
    int r2   = w >> 1, c2 = w & 1;
    int q    = lane >> 4;
    int l16  = lane & 15;
    int row0 = blockIdx.x * 128;

    f32x4 acc[4][4];
#pragma unroll
    for (int i = 0; i < 4; ++i)
#pragma unroll
        for (int j = 0; j < 4; ++j) acc[i][j] = 0.f;

    const ushort* Asrc[3] = {a0b, a1b, xb};

    for (int kt = 0; kt < 384; kt += 32) {
        const ushort* Ab = Asrc[kt >> 7];
        int ko = kt & 127;
#pragma unroll
        for (int h = 0; h < 2; ++h) {
            int s  = t + h * 256;
            int r  = s >> 2;
            int q4 = s & 3;
            int rg = row0 + r;
            uint4 av = make_uint4(0, 0, 0, 0);
            if (rg < N) av = *(const uint4*)(Ab + (size_t)rg * 128 + ko + q4 * 8);
            *(uint4*)&As[r * LST + q4 * 8] = av;
            uint4 bv = *(const uint4*)(Wt + (size_t)r * 384 + kt + q4 * 8);
            *(uint4*)&Bs[r * LST + q4 * 8] = bv;
        }
        __syncthreads();
        short8 af[4], bf[4];
#pragma unroll
        for (int mt = 0; mt < 4; ++mt)
            af[mt] = *(const short8*)&As[(r2 * 64 + mt * 16 + l16) * LST + q * 8];
#pragma unroll
        for (int nt = 0; nt < 4; ++nt)
            bf[nt] = *(const short8*)&Bs[(c2 * 64 + nt * 16 + l16) * LST + q * 8];
#pragma unroll
        for (int mt = 0; mt < 4; ++mt)
#pragma unroll
            for (int nt = 0; nt < 4; ++nt)
                acc[mt][nt] = __builtin_amdgcn_mfma_f32_16x16x32_bf16(
                    af[mt], bf[nt], acc[mt][nt], 0, 0, 0);
        __syncthreads();
    }

#pragma unroll
    for (int nt = 0; nt < 4; ++nt) {
        int col = c2 * 64 + nt * 16 + l16;
        float bb = bias[col];
#pragma unroll
        for (int mt = 0; mt < 4; ++mt) {
#pragma unroll
            for (int r = 0; r < 4; ++r) {
                int row = row0 + r2 * 64 + mt * 16 + q * 4 + r;
                if (row < N) out[(size_t)row * 128 + col] = acc[mt][nt][r] + bb;
            }
        }
    }
}

// ------------------------------------------------------------------ launch
extern "C" void kernel_launch(void* const* d_in, const int* in_sizes, int n_in,
                              void* d_out, int out_size, void* d_ws, size_t ws_size,
                              hipStream_t stream) {
    const float* x    = (const float*)d_in[0];
    const int*   ei   = (const int*)d_in[1];   // [2, E] int32
    const float* ea   = (const float*)d_in[2]; // [E, 1]
    const float* W    = (const float*)d_in[3]; // [2, 128, 128]
    const float* Wr   = (const float*)d_in[4]; // [128, 128]
    const float* bias = (const float*)d_in[5]; // [128]
    float* out = (float*)d_out;

    char* ws = (char*)d_ws;
    size_t o = 0;
    auto alloc = [&](size_t bytes) -> void* {
        void* p = ws + o;
        o = (o + bytes + 255) & ~(size_t)255;
        return p;
    };
    int*    gcur = (int*)alloc((size_t)NB * 4);
    uint*   pay  = (uint*)alloc((size_t)NB * BKT_CAP * 4);
    ushort* xb   = (ushort*)alloc((size_t)N * D * 2);
    ushort* a0b  = (ushort*)alloc((size_t)N * D * 2);
    ushort* a1b  = (ushort*)alloc((size_t)N * D * 2);
    ushort* Wt   = (ushort*)alloc((size_t)128 * 384 * 2);
    (void)ws_size; (void)in_sizes; (void)n_in; (void)out_size;

    prep_k   <<<PREP_CVT_BLKS + PREP_W_BLKS + 1, 1024, 0, stream>>>(
                 x, W, Wr, xb, Wt, gcur);
    bin_k    <<<BINBLK, 1024, 0, stream>>>(ei, ea, gcur, pay);
    sortagg_k<<<NB, 1024, 0, stream>>>(xb, gcur, pay, a0b, a1b);
    gemm_k   <<<(N + 127) / 128, 256, 0, stream>>>(a0b, a1b, xb, Wt, bias, out);
}

// Round 9
// 198.838 us; speedup vs baseline: 1.0052x; 1.0052x over previous
//
#include <hip/hip_runtime.h>

static constexpr int N = 50000;      // nodes
static constexpr int E = 1600000;    // edges
static constexpr int D = 128;        // feature dim (in == out)
static constexpr int NB = (N + 63) / 64;         // 782 buckets of 64 nodes
static constexpr int BINBLK = 256;               // bin blocks (E divides evenly)
static constexpr int CHUNK = E / BINBLK;         // 6250 edges per bin block
static constexpr int BKT_CAP = 3072;             // slab size; mean 2048, ~22 sigma
static constexpr int QD = 12;                    // LDS queue depth per bucket
static constexpr int GR = 8;                     // flush granularity (32B runs)

typedef __attribute__((ext_vector_type(8))) short short8;   // 8 bf16
typedef __attribute__((ext_vector_type(4))) float f32x4;    // 4 fp32
typedef __attribute__((ext_vector_type(2))) float f32x2;    // 2 fp32 (pk ops)

__device__ __forceinline__ uint bf16rne2(float a, float b) {
    uint ua = __float_as_uint(a), ub = __float_as_uint(b);
    ua += 0x7fffu + ((ua >> 16) & 1u);
    ub += 0x7fffu + ((ub >> 16) & 1u);
    return (ua >> 16) | (ub & 0xffff0000u);
}

// ------------------------------------------------------------ fused prep
// blocks [0,1563): x fp32->bf16 (N*D/4 = 1.6M uint2 items).
// [1563,1611): weight transpose+bf16.  block 1611: zero bucket cursors.
static constexpr int PREP_CVT_BLKS = (N * D / 4 + 1023) / 1024;  // 1563
static constexpr int PREP_W_BLKS   = 48;         // 128*384/1024
__global__ __launch_bounds__(1024) void prep_k(
        const float* __restrict__ x, const float* __restrict__ W,
        const float* __restrict__ Wr, ushort* __restrict__ xb,
        ushort* __restrict__ Wt, int* __restrict__ gcur) {
    int b = blockIdx.x, t = threadIdx.x;
    if (b < PREP_CVT_BLKS) {
        int i = b * 1024 + t;
        if (i < N * D / 4) {
            float4 v = ((const float4*)x)[i];
            uint2 o = { bf16rne2(v.x, v.y), bf16rne2(v.z, v.w) };
            ((uint2*)xb)[i] = o;
        }
    } else if (b < PREP_CVT_BLKS + PREP_W_BLKS) {
        int i = (b - PREP_CVT_BLKS) * 1024 + t;   // < 128*384
        int n = i / 384, r = i % 384;
        float v = (r < 256) ? W[(size_t)r * 128 + n]
                            : Wr[(size_t)(r - 256) * 128 + n];
        uint u = __float_as_uint(v);
        u += 0x7fffu + ((u >> 16) & 1u);
        Wt[(size_t)n * 384 + r] = (ushort)(u >> 16);
    } else {
        if (t < NB) gcur[t] = 0;
    }
}

// -------------------------------------------------- binning, LDS run-former
// Per-bucket LDS queues; flush full 8-entry groups per round as single-thread
// bursts of consecutive scalar stores (L2 write-combines into whole lines).
// Payload: [15:0]=src, [21:16]=dst&63, [31:22]=u quantized /1023.
__device__ __forceinline__ int logical_blk() {
    // XCD swizzle: adjacent chunks -> same XCD so adjacent slab runs share L2.
    return (blockIdx.x & 7) * (BINBLK / 8) + (blockIdx.x >> 3);
}

__global__ __launch_bounds__(1024) void bin_k(const int* __restrict__ ei,
                                              const float* __restrict__ ea,
                                              int* __restrict__ gcur,
                                              uint* __restrict__ pay) {
    __shared__ uint q[NB][QD];
    __shared__ int qn[NB];
    int t = threadIdx.x;
    int b = logical_blk();
    for (int j = t; j < NB; j += 1024) qn[j] = 0;
    __syncthreads();
    int b0 = b * CHUNK;
    for (int r0 = 0; r0 < CHUNK; r0 += 1024) {
        int rt = r0 + t;
        if (rt < CHUNK) {
            int i = b0 + rt;
            int dst = ei[E + i];
            if ((unsigned)dst < (unsigned)N) {
                int src = ei[i];
                float u = fminf(fmaxf(ea[i], 0.0f), 1.0f);
                uint u10 = (uint)(u * 1023.0f + 0.5f);
                uint p = (u10 << 22) | ((uint)(dst & 63) << 16) | (uint)src;
                int bkt = dst >> 6;
                int pos = atomicAdd(&qn[bkt], 1);
                if (pos < QD) q[bkt][pos] = p;
                else {                       // rare overflow: direct append
                    int gp = atomicAdd(&gcur[bkt], 1);
                    if (gp < BKT_CAP) pay[(size_t)bkt * BKT_CAP + gp] = p;
                }
            }
        }
        __syncthreads();
        if (t < NB) {
            int n = qn[t]; if (n > QD) n = QD;
            int nf = n & ~(GR - 1);
            if (nf) {
                int gp = atomicAdd(&gcur[t], nf);
                uint* dp = pay + (size_t)t * BKT_CAP;
#pragma unroll 1
                for (int k = 0; k < nf; ++k)
                    if (gp + k < BKT_CAP) dp[gp + k] = q[t][k];
                for (int k = 0; k < n - nf; ++k) q[t][k] = q[t][nf + k];
                qn[t] = n - nf;
            }
        }
        __syncthreads();
    }
    // final residue flush (consecutive burst per bucket)
    if (t < NB) {
        int n = qn[t]; if (n > QD) n = QD;
        if (n) {
            int gp = atomicAdd(&gcur[t], n);
            uint* dp = pay + (size_t)t * BKT_CAP;
            for (int k = 0; k < n; ++k)
                if (gp + k < BKT_CAP) dp[gp + k] = q[t][k];
        }
    }
}

// --------------------------- fused per-bucket sort + per-node aggregation
// One 1024-thread WG per bucket (64 nodes). Phase 1: LDS-rank payload by
// dst_low6. Phase 2: 16 waves x 4 groups of 16 lanes; group = node; lane =
// 8 channels. 4-deep row-gather pipeline for L3-latency hiding.
__global__ __launch_bounds__(1024) void sortagg_k(
        const ushort* __restrict__ xb, const int* __restrict__ gcur,
        const uint* __restrict__ pay, ushort* __restrict__ a0b,
        ushort* __restrict__ a1b) {
    __shared__ uint srt[BKT_CAP];
    __shared__ int hist[64];
    __shared__ int off64[65];
    int b = blockIdx.x, t = threadIdx.x;
    int beg = b * BKT_CAP;
    int c = gcur[b];
    if (c > BKT_CAP) c = BKT_CAP;
    if (t < 64) hist[t] = 0;
    __syncthreads();
    uint mypay[3]; int myrank[3];
#pragma unroll
    for (int k = 0; k < 3; ++k) {
        int i = t + k * 1024;
        if (i < c) {
            uint p = pay[beg + i];
            mypay[k] = p;
            myrank[k] = atomicAdd(&hist[(p >> 16) & 63], 1);
        }
    }
    __syncthreads();
    if (t < 64) {
        int v = hist[t];
        int s = v;
        for (int d = 1; d < 64; d <<= 1) {
            int o = __shfl_up(s, d);
            if (t >= d) s += o;
        }
        off64[t] = s - v;             // exclusive
        if (t == 63) off64[64] = s;
    }
    __syncthreads();
#pragma unroll
    for (int k = 0; k < 3; ++k) {
        int i = t + k * 1024;
        if (i < c) {
            uint p = mypay[k];
            srt[off64[(p >> 16) & 63] + myrank[k]] = p;
        }
    }
    __syncthreads();

    // ---- aggregation: group (wave, grp) -> local node nloc
    int lane = t & 63;
    int wv   = t >> 6;            // 0..15
    int grp  = (lane >> 4);       // 0..3
    int cl   = lane & 15;         // channel block: chs [8*cl, 8*cl+8)
    int nloc = wv * 4 + grp;      // 0..63
    int s0 = off64[nloc], s1 = off64[nloc + 1];
    int deg = s1 - s0;

    f32x2 S[4], T[4];
#pragma unroll
    for (int q = 0; q < 4; ++q) { S[q] = 0.f; T[q] = 0.f; }

    int j = s0;
    for (; j + 3 < s1; j += 4) {           // 4-deep gather pipeline
        uint p[4];
        uint4 v[4];
#pragma unroll
        for (int d = 0; d < 4; ++d) p[d] = srt[j + d];
#pragma unroll
        for (int d = 0; d < 4; ++d)
            v[d] = *(const uint4*)(xb + (size_t)(p[d] & 0xffffu) * D + cl * 8);
#pragma unroll
        for (int d = 0; d < 4; ++d) {
            float u = (float)(p[d] >> 22) * (1.0f / 1023.0f);
            f32x2 u2 = {u, u};
            uint w[4] = {v[d].x, v[d].y, v[d].z, v[d].w};
#pragma unroll
            for (int q = 0; q < 4; ++q) {
                f32x2 xv = { __uint_as_float(w[q] << 16),
                             __uint_as_float(w[q] & 0xffff0000u) };
                S[q] += xv;
                T[q] = u2 * xv + T[q];
            }
        }
    }
    for (; j < s1; ++j) {
        uint p0 = srt[j];
        uint4 v0 = *(const uint4*)(xb + (size_t)(p0 & 0xffffu) * D + cl * 8);
        float u = (float)(p0 >> 22) * (1.0f / 1023.0f);
        f32x2 u2 = {u, u};
        uint w[4] = {v0.x, v0.y, v0.z, v0.w};
#pragma unroll
        for (int q = 0; q < 4; ++q) {
            f32x2 xv = { __uint_as_float(w[q] << 16),
                         __uint_as_float(w[q] & 0xffff0000u) };
            S[q] += xv;
            T[q] = u2 * xv + T[q];
        }
    }

    int node = b * 64 + nloc;
    if (node < N) {
        float inv = 1.0f / fmaxf((float)deg, 1.0f);
        uint4 oa = { bf16rne2((S[0].x - T[0].x) * inv, (S[0].y - T[0].y) * inv),
                     bf16rne2((S[1].x - T[1].x) * inv, (S[1].y - T[1].y) * inv),
                     bf16rne2((S[2].x - T[2].x) * inv, (S[2].y - T[2].y) * inv),
                     bf16rne2((S[3].x - T[3].x) * inv, (S[3].y - T[3].y) * inv) };
        uint4 ob = { bf16rne2(T[0].x * inv, T[0].y * inv),
                     bf16rne2(T[1].x * inv, T[1].y * inv),
                     bf16rne2(T[2].x * inv, T[2].y * inv),
                     bf16rne2(T[3].x * inv, T[3].y * inv) };
        *(uint4*)(a0b + (size_t)node * D + cl * 8) = oa;
        *(uint4*)(a1b + (size_t)node * D + cl * 8) = ob;
    }
}

// ------------------------------------------------------------- output GEMM
// out = [a0|a1|x] (M=50000, K=384, bf16) @ Wt^T + bias. 128x128 tile,
// 4 waves 2x2, 16x16x32 bf16 MFMA, BK=32.
__global__ __launch_bounds__(256) void gemm_k(
        const ushort* __restrict__ a0b, const ushort* __restrict__ a1b,
        const ushort* __restrict__ xb, const ushort* __restrict__ Wt,
        const float* __restrict__ bias, float* __restrict__ out) {
    constexpr int LST = 40;
    __shared__ ushort As[128 * LST];
    __shared__ ushort Bs[128 * LST];

    int t    = threadIdx.x;
    int lane = t & 63;
    int w    = t >> 6;
    int r2   = w >> 1, c2 = w & 1;
    int q    = lane >> 4;
    int l16  = lane & 15;
    int row0 = blockIdx.x * 128;

    f32x4 acc[4][4];
#pragma unroll
    for (int i = 0; i < 4; ++i)
#pragma unroll
        for (int j = 0; j < 4; ++j) acc[i][j] = 0.f;

    const ushort* Asrc[3] = {a0b, a1b, xb};

    for (int kt = 0; kt < 384; kt += 32) {
        const ushort* Ab = Asrc[kt >> 7];
        int ko = kt & 127;
#pragma unroll
        for (int h = 0; h < 2; ++h) {
            int s  = t + h * 256;
            int r  = s >> 2;
            int q4 = s & 3;
            int rg = row0 + r;
            uint4 av = make_uint4(0, 0, 0, 0);
            if (rg < N) av = *(const uint4*)(Ab + (size_t)rg * 128 + ko + q4 * 8);
            *(uint4*)&As[r * LST + q4 * 8] = av;
            uint4 bv = *(const uint4*)(Wt + (size_t)r * 384 + kt + q4 * 8);
            *(uint4*)&Bs[r * LST + q4 * 8] = bv;
        }
        __syncthreads();
        short8 af[4], bf[4];
#pragma unroll
        for (int mt = 0; mt < 4; ++mt)
            af[mt] = *(const short8*)&As[(r2 * 64 + mt * 16 + l16) * LST + q * 8];
#pragma unroll
        for (int nt = 0; nt < 4; ++nt)
            bf[nt] = *(const short8*)&Bs[(c2 * 64 + nt * 16 + l16) * LST + q * 8];
#pragma unroll
        for (int mt = 0; mt < 4; ++mt)
#pragma unroll
            for (int nt = 0; nt < 4; ++nt)
                acc[mt][nt] = __builtin_amdgcn_mfma_f32_16x16x32_bf16(
                    af[mt], bf[nt], acc[mt][nt], 0, 0, 0);
        __syncthreads();
    }

#pragma unroll
    for (int nt = 0; nt < 4; ++nt) {
        int col = c2 * 64 + nt * 16 + l16;
        float bb = bias[col];
#pragma unroll
        for (int mt = 0; mt < 4; ++mt) {
#pragma unroll
            for (int r = 0; r < 4; ++r) {
                int row = row0 + r2 * 64 + mt * 16 + q * 4 + r;
                if (row < N) out[(size_t)row * 128 + col] = acc[mt][nt][r] + bb;
            }
        }
    }
}

// ------------------------------------------------------------------ launch
extern "C" void kernel_launch(void* const* d_in, const int* in_sizes, int n_in,
                              void* d_out, int out_size, void* d_ws, size_t ws_size,
                              hipStream_t stream) {
    const float* x    = (const float*)d_in[0];
    const int*   ei   = (const int*)d_in[1];   // [2, E] int32
    const float* ea   = (const float*)d_in[2]; // [E, 1]
    const float* W    = (const float*)d_in[3]; // [2, 128, 128]
    const float* Wr   = (const float*)d_in[4]; // [128, 128]
    const float* bias = (const float*)d_in[5]; // [128]
    float* out = (float*)d_out;

    char* ws = (char*)d_ws;
    size_t o = 0;
    auto alloc = [&](size_t bytes) -> void* {
        void* p = ws + o;
        o = (o + bytes + 255) & ~(size_t)255;
        return p;
    };
    int*    gcur = (int*)alloc((size_t)NB * 4);
    uint*   pay  = (uint*)alloc((size_t)NB * BKT_CAP * 4);
    ushort* xb   = (ushort*)alloc((size_t)N * D * 2);
    ushort* a0b  = (ushort*)alloc((size_t)N * D * 2);
    ushort* a1b  = (ushort*)alloc((size_t)N * D * 2);
    ushort* Wt   = (ushort*)alloc((size_t)128 * 384 * 2);
    (void)ws_size; (void)in_sizes; (void)n_in; (void)out_size;

    prep_k   <<<PREP_CVT_BLKS + PREP_W_BLKS + 1, 1024, 0, stream>>>(
                 x, W, Wr, xb, Wt, gcur);
    bin_k    <<<BINBLK, 1024, 0, stream>>>(ei, ea, gcur, pay);
    sortagg_k<<<NB, 1024, 0, stream>>>(xb, gcur, pay, a0b, a1b);
    gemm_k   <<<(N + 127) / 128, 256, 0, stream>>>(a0b, a1b, xb, Wt, bias, out);
}

// Round 10
// 176.167 us; speedup vs baseline: 1.1345x; 1.1287x over previous
//
#include <hip/hip_runtime.h>

static constexpr int N = 50000;      // nodes
static constexpr int E = 1600000;    // edges
static constexpr int D = 128;        // feature dim (in == out)
static constexpr int NB = (N + 63) / 64;         // 782 buckets of 64 nodes
static constexpr int BIN_BLKS = 512;             // bin chunks (E divides evenly)
static constexpr int CHUNK = E / BIN_BLKS;       // 3125 edges per bin block
static constexpr int BKT_CAP = 3072;             // slab size; mean 2048, ~22 sigma
static constexpr int CVT_BLKS = (N * D / 8 + 1023) / 1024;   // 782
static constexpr int W_BLKS = 48;                // 128*384/1024

typedef __attribute__((ext_vector_type(8))) short short8;   // 8 bf16
typedef __attribute__((ext_vector_type(4))) float f32x4;    // 4 fp32
typedef __attribute__((ext_vector_type(2))) float f32x2;    // 2 fp32 (pk ops)

__device__ __forceinline__ uint bf16rne2(float a, float b) {
    uint ua = __float_as_uint(a), ub = __float_as_uint(b);
    ua += 0x7fffu + ((ua >> 16) & 1u);
    ub += 0x7fffu + ((ub >> 16) & 1u);
    return (ua >> 16) | (ub & 0xffff0000u);
}

// ---------------------------------------------- fused bin + prep mega-kernel
// blocks [0,512): bin edges into per-bucket slabs (R8 scheme: LDS hist,
//   one cursor atomic per (block,bucket), scatter).
// [512,1294): x fp32 -> bf16 (for GEMM) + fp8 e4m3 (for gather), one x read.
// [1294,1342): weight transpose + bf16.
// Payload: [15:0]=src, [21:16]=dst&63, [31:22]=u quantized /1023.
__device__ __forceinline__ int logical_blk() {
    // XCD swizzle: adjacent chunks -> same XCD so adjacent slab runs share L2.
    return (blockIdx.x & 7) * (BIN_BLKS / 8) + (blockIdx.x >> 3);
}

__global__ __launch_bounds__(1024) void binprep_k(
        const int* __restrict__ ei, const float* __restrict__ ea,
        const float* __restrict__ x, const float* __restrict__ W,
        const float* __restrict__ Wr, int* __restrict__ gcur,
        uint* __restrict__ pay, ushort* __restrict__ xb,
        uchar* __restrict__ xf8, ushort* __restrict__ Wt) {
    __shared__ int hist[NB];
    __shared__ int base[NB];
    int t = threadIdx.x;
    if (blockIdx.x < BIN_BLKS) {
        int b = logical_blk();
        for (int j = t; j < NB; j += 1024) hist[j] = 0;
        __syncthreads();
        int b0 = b * CHUNK;
        for (int i = b0 + t; i < b0 + CHUNK; i += 1024) {
            int dst = ei[E + i];
            if ((unsigned)dst < (unsigned)N) atomicAdd(&hist[dst >> 6], 1);
        }
        __syncthreads();
        for (int j = t; j < NB; j += 1024) {
            int c = hist[j];
            base[j] = c ? atomicAdd(&gcur[j], c) : 0;
            hist[j] = 0;
        }
        __syncthreads();
        for (int i = b0 + t; i < b0 + CHUNK; i += 1024) {
            int dst = ei[E + i];
            if ((unsigned)dst >= (unsigned)N) continue;
            int src = ei[i];
            float u = fminf(fmaxf(ea[i], 0.0f), 1.0f);
            uint u10 = (uint)(u * 1023.0f + 0.5f);
            int bkt = dst >> 6;
            int r = atomicAdd(&hist[bkt], 1);
            int pos = base[bkt] + r;
            if (pos < BKT_CAP)                       // slab overflow guard
                pay[(size_t)bkt * BKT_CAP + pos] =
                    (u10 << 22) | ((uint)(dst & 63) << 16) | (uint)src;
        }
    } else if (blockIdx.x < BIN_BLKS + CVT_BLKS) {
        int i = (blockIdx.x - BIN_BLKS) * 1024 + t;  // 8-float items
        if (i < N * D / 8) {
            float4 v0 = ((const float4*)x)[2 * i];
            float4 v1 = ((const float4*)x)[2 * i + 1];
            uint4 ob = { bf16rne2(v0.x, v0.y), bf16rne2(v0.z, v0.w),
                         bf16rne2(v1.x, v1.y), bf16rne2(v1.z, v1.w) };
            ((uint4*)xb)[i] = ob;
            int lo = __builtin_amdgcn_cvt_pk_fp8_f32(v0.x, v0.y, 0, false);
            lo = __builtin_amdgcn_cvt_pk_fp8_f32(v0.z, v0.w, lo, true);
            int hi = __builtin_amdgcn_cvt_pk_fp8_f32(v1.x, v1.y, 0, false);
            hi = __builtin_amdgcn_cvt_pk_fp8_f32(v1.z, v1.w, hi, true);
            uint2 o8 = { (uint)lo, (uint)hi };
            ((uint2*)xf8)[i] = o8;
        }
    } else {
        int i = (blockIdx.x - BIN_BLKS - CVT_BLKS) * 1024 + t;  // < 128*384
        int n = i / 384, r = i % 384;
        float v = (r < 256) ? W[(size_t)r * 128 + n]
                            : Wr[(size_t)(r - 256) * 128 + n];
        uint u = __float_as_uint(v);
        u += 0x7fffu + ((u >> 16) & 1u);
        Wt[(size_t)n * 384 + r] = (ushort)(u >> 16);
    }
}

// --------------------------- fused per-bucket sort + per-node aggregation
// One 1024-thread WG per bucket (64 nodes). Phase 1: LDS-rank payload by
// dst_low6. Phase 2: 16 waves x 4 groups of 16 lanes; group = node; lane =
// 8 channels. fp8 row gather (128 B/edge), HW cvt_pk_f32_fp8 decode,
// 4-deep gather pipeline for L3-latency hiding.
__global__ __launch_bounds__(1024) void sortagg_k(
        const uchar* __restrict__ xf8, const int* __restrict__ gcur,
        const uint* __restrict__ pay, ushort* __restrict__ a0b,
        ushort* __restrict__ a1b) {
    __shared__ uint srt[BKT_CAP];
    __shared__ int hist[64];
    __shared__ int off64[65];
    int b = blockIdx.x, t = threadIdx.x;
    int beg = b * BKT_CAP;
    int c = gcur[b];
    if (c > BKT_CAP) c = BKT_CAP;
    if (t < 64) hist[t] = 0;
    __syncthreads();
    uint mypay[3]; int myrank[3];
#pragma unroll
    for (int k = 0; k < 3; ++k) {
        int i = t + k * 1024;
        if (i < c) {
            uint p = pay[beg + i];
            mypay[k] = p;
            myrank[k] = atomicAdd(&hist[(p >> 16) & 63], 1);
        }
    }
    __syncthreads();
    if (t < 64) {
        int v = hist[t];
        int s = v;
        for (int d = 1; d < 64; d <<= 1) {
            int o = __shfl_up(s, d);
            if (t >= d) s += o;
        }
        off64[t] = s - v;             // exclusive
        if (t == 63) off64[64] = s;
    }
    __syncthreads();
#pragma unroll
    for (int k = 0; k < 3; ++k) {
        int i = t + k * 1024;
        if (i < c) {
            uint p = mypay[k];
            srt[off64[(p >> 16) & 63] + myrank[k]] = p;
        }
    }
    __syncthreads();

    // ---- aggregation: group (wave, grp) -> local node nloc
    int lane = t & 63;
    int wv   = t >> 6;            // 0..15
    int grp  = (lane >> 4);       // 0..3
    int cl   = lane & 15;         // channel block: chs [8*cl, 8*cl+8)
    int nloc = wv * 4 + grp;      // 0..63
    int s0 = off64[nloc], s1 = off64[nloc + 1];
    int deg = s1 - s0;

    f32x2 S[4], T[4];
#pragma unroll
    for (int q = 0; q < 4; ++q) { S[q] = 0.f; T[q] = 0.f; }

    int j = s0;
    for (; j + 3 < s1; j += 4) {           // 4-deep gather pipeline
        uint p[4];
        uint2 v[4];
#pragma unroll
        for (int d = 0; d < 4; ++d) p[d] = srt[j + d];
#pragma unroll
        for (int d = 0; d < 4; ++d)
            v[d] = *(const uint2*)(xf8 + (size_t)(p[d] & 0xffffu) * D + cl * 8);
#pragma unroll
        for (int d = 0; d < 4; ++d) {
            float u = (float)(p[d] >> 22) * (1.0f / 1023.0f);
            f32x2 u2 = {u, u};
            f32x2 xv0 = __builtin_amdgcn_cvt_pk_f32_fp8((int)v[d].x, false);
            f32x2 xv1 = __builtin_amdgcn_cvt_pk_f32_fp8((int)v[d].x, true);
            f32x2 xv2 = __builtin_amdgcn_cvt_pk_f32_fp8((int)v[d].y, false);
            f32x2 xv3 = __builtin_amdgcn_cvt_pk_f32_fp8((int)v[d].y, true);
            S[0] += xv0; T[0] = u2 * xv0 + T[0];
            S[1] += xv1; T[1] = u2 * xv1 + T[1];
            S[2] += xv2; T[2] = u2 * xv2 + T[2];
            S[3] += xv3; T[3] = u2 * xv3 + T[3];
        }
    }
    for (; j < s1; ++j) {
        uint p0 = srt[j];
        uint2 v0 = *(const uint2*)(xf8 + (size_t)(p0 & 0xffffu) * D + cl * 8);
        float u = (float)(p0 >> 22) * (1.0f / 1023.0f);
        f32x2 u2 = {u, u};
        f32x2 xv0 = __builtin_amdgcn_cvt_pk_f32_fp8((int)v0.x, false);
        f32x2 xv1 = __builtin_amdgcn_cvt_pk_f32_fp8((int)v0.x, true);
        f32x2 xv2 = __builtin_amdgcn_cvt_pk_f32_fp8((int)v0.y, false);
        f32x2 xv3 = __builtin_amdgcn_cvt_pk_f32_fp8((int)v0.y, true);
        S[0] += xv0; T[0] = u2 * xv0 + T[0];
        S[1] += xv1; T[1] = u2 * xv1 + T[1];
        S[2] += xv2; T[2] = u2 * xv2 + T[2];
        S[3] += xv3; T[3] = u2 * xv3 + T[3];
    }

    int node = b * 64 + nloc;
    if (node < N) {
        float inv = 1.0f / fmaxf((float)deg, 1.0f);
        uint4 oa = { bf16rne2((S[0].x - T[0].x) * inv, (S[0].y - T[0].y) * inv),
                     bf16rne2((S[1].x - T[1].x) * inv, (S[1].y - T[1].y) * inv),
                     bf16rne2((S[2].x - T[2].x) * inv, (S[2].y - T[2].y) * inv),
                     bf16rne2((S[3].x - T[3].x) * inv, (S[3].y - T[3].y) * inv) };
        uint4 ob = { bf16rne2(T[0].x * inv, T[0].y * inv),
                     bf16rne2(T[1].x * inv, T[1].y * inv),
                     bf16rne2(T[2].x * inv, T[2].y * inv),
                     bf16rne2(T[3].x * inv, T[3].y * inv) };
        *(uint4*)(a0b + (size_t)node * D + cl * 8) = oa;
        *(uint4*)(a1b + (size_t)node * D + cl * 8) = ob;
    }
}

// ------------------------------------------------------------- output GEMM
// out = [a0|a1|x] (M=50000, K=384, bf16) @ Wt^T + bias. 128x128 tile,
// 4 waves 2x2, 16x16x32 bf16 MFMA, BK=32.
__global__ __launch_bounds__(256) void gemm_k(
        const ushort* __restrict__ a0b, const ushort* __restrict__ a1b,
        const ushort* __restrict__ xb, const ushort* __restrict__ Wt,
        const float* __restrict__ bias, float* __restrict__ out) {
    constexpr int LST = 40;
    __shared__ ushort As[128 * LST];
    __shared__ ushort Bs[128 * LST];

    int t    = threadIdx.x;
    int lane = t & 63;
    int w    = t >> 6;
    int r2   = w >> 1, c2 = w & 1;
    int q    = lane >> 4;
    int l16  = lane & 15;
    int row0 = blockIdx.x * 128;

    f32x4 acc[4][4];
#pragma unroll
    for (int i = 0; i < 4; ++i)
#pragma unroll
        for (int j = 0; j < 4; ++j) acc[i][j] = 0.f;

    const ushort* Asrc[3] = {a0b, a1b, xb};

    for (int kt = 0; kt < 384; kt += 32) {
        const ushort* Ab = Asrc[kt >> 7];
        int ko = kt & 127;
#pragma unroll
        for (int h = 0; h < 2; ++h) {
            int s  = t + h * 256;
            int r  = s >> 2;
            int q4 = s & 3;
            int rg = row0 + r;
            uint4 av = make_uint4(0, 0, 0, 0);
            if (rg < N) av = *(const uint4*)(Ab + (size_t)rg * 128 + ko + q4 * 8);
            *(uint4*)&As[r * LST + q4 * 8] = av;
            uint4 bv = *(const uint4*)(Wt + (size_t)r * 384 + kt + q4 * 8);
            *(uint4*)&Bs[r * LST + q4 * 8] = bv;
        }
        __syncthreads();
        short8 af[4], bf[4];
#pragma unroll
        for (int mt = 0; mt < 4; ++mt)
            af[mt] = *(const short8*)&As[(r2 * 64 + mt * 16 + l16) * LST + q * 8];
#pragma unroll
        for (int nt = 0; nt < 4; ++nt)
            bf[nt] = *(const short8*)&Bs[(c2 * 64 + nt * 16 + l16) * LST + q * 8];
#pragma unroll
        for (int mt = 0; mt < 4; ++mt)
#pragma unroll
            for (int nt = 0; nt < 4; ++nt)
                acc[mt][nt] = __builtin_amdgcn_mfma_f32_16x16x32_bf16(
                    af[mt], bf[nt], acc[mt][nt], 0, 0, 0);
        __syncthreads();
    }

#pragma unroll
    for (int nt = 0; nt < 4; ++nt) {
        int col = c2 * 64 + nt * 16 + l16;
        float bb = bias[col];
#pragma unroll
        for (int mt = 0; mt < 4; ++mt) {
#pragma unroll
            for (int r = 0; r < 4; ++r) {
                int row = row0 + r2 * 64 + mt * 16 + q * 4 + r;
                if (row < N) out[(size_t)row * 128 + col] = acc[mt][nt][r] + bb;
            }
        }
    }
}

// ------------------------------------------------------------------ launch
extern "C" void kernel_launch(void* const* d_in, const int* in_sizes, int n_in,
                              void* d_out, int out_size, void* d_ws, size_t ws_size,
                              hipStream_t stream) {
    const float* x    = (const float*)d_in[0];
    const int*   ei   = (const int*)d_in[1];   // [2, E] int32
    const float* ea   = (const float*)d_in[2]; // [E, 1]
    const float* W    = (const float*)d_in[3]; // [2, 128, 128]
    const float* Wr   = (const float*)d_in[4]; // [128, 128]
    const float* bias = (const float*)d_in[5]; // [128]
    float* out = (float*)d_out;

    char* ws = (char*)d_ws;
    size_t o = 0;
    auto alloc = [&](size_t bytes) -> void* {
        void* p = ws + o;
        o = (o + bytes + 255) & ~(size_t)255;
        return p;
    };
    int*    gcur = (int*)alloc((size_t)NB * 4);
    uint*   pay  = (uint*)alloc((size_t)NB * BKT_CAP * 4);
    ushort* xb   = (ushort*)alloc((size_t)N * D * 2);
    uchar*  xf8  = (uchar*)alloc((size_t)N * D);
    ushort* a0b  = (ushort*)alloc((size_t)N * D * 2);
    ushort* a1b  = (ushort*)alloc((size_t)N * D * 2);
    ushort* Wt   = (ushort*)alloc((size_t)128 * 384 * 2);
    (void)ws_size; (void)in_sizes; (void)n_in; (void)out_size;

    hipMemsetAsync(gcur, 0, (size_t)NB * 4, stream);
    binprep_k<<<BIN_BLKS + CVT_BLKS + W_BLKS, 1024, 0, stream>>>(
                 ei, ea, x, W, Wr, gcur, pay, xb, xf8, Wt);
    sortagg_k<<<NB, 1024, 0, stream>>>(xf8, gcur, pay, a0b, a1b);
    gemm_k   <<<(N + 127) / 128, 256, 0, stream>>>(a0b, a1b, xb, Wt, bias, out);
}